// Round 13
// baseline (203.872 us; speedup 1.0000x reference)
//
#include <hip/hip_runtime.h>
#include <hip/hip_fp16.h>

// Problem constants (fixed by the reference): B=2, T=2048, E=1024, H=16, d=64
#define B_NUM  2
#define T_DIM  2048
#define E_DIM  1024
#define H_NUM  16
#define D_HEAD 64
#define BH_NUM (B_NUM * H_NUM)
#define NT     (T_DIM / 64)

using half8  = __attribute__((ext_vector_type(8))) _Float16;
using half4v = __attribute__((ext_vector_type(4))) _Float16;
using f32x4  = __attribute__((ext_vector_type(4))) float;

#define AS1 __attribute__((address_space(1)))
#define AS3 __attribute__((address_space(3)))

// 1/sqrt(64) * log2(e): MFMA yields S*log2e, so v_exp_f32 (2^x) == exp(S)
#define QSCALE 0.18033688011112042f

// Mid-tile barrier: retire the previous cooperative stage (own-wave count N =
// number of VMEM ops issued AFTER the target stage), then sync.
#define BAR_VM(N)                                                       \
    do {                                                                \
        asm volatile("s_waitcnt vmcnt(" #N ")" ::: "memory");           \
        __builtin_amdgcn_s_barrier();                                   \
        __builtin_amdgcn_sched_barrier(0);                              \
    } while (0)

// End-of-tile barrier: all waves finished READING the current LDS buffer.
__device__ __forceinline__ void bar_plain() {
    __builtin_amdgcn_s_barrier();
    __builtin_amdgcn_sched_barrier(0);
}

// ---------------------------------------------------------------------------
// merged prep: blocks [0,1024) transpose V -> Vt; blocks [1024,2304) cast
// K and W to f16 (grid-stride).
// ---------------------------------------------------------------------------
#define TP_BLOCKS  (NT * BH_NUM)          // 1024
#define CAST_BLOCKS 1280
__global__ void prep_kernel(const float* __restrict__ kin,
                            const float* __restrict__ win,
                            const float* __restrict__ V,
                            _Float16* __restrict__ Kh,
                            _Float16* __restrict__ Wh,
                            _Float16* __restrict__ Vt,
                            int nk4, int ntot4) {
    __shared__ float tile[64][65];
    int t = threadIdx.x;

    if (blockIdx.x < TP_BLOCKS) {
        int s0 = (blockIdx.x & 31) * 64;
        int bh = blockIdx.x >> 5;
        int b = bh >> 4, h = bh & 15;

        int row = t >> 2;
        int c0  = (t & 3) * 16;
        const float* src = V + ((size_t)(b * T_DIM + s0 + row)) * E_DIM + h * D_HEAD + c0;
#pragma unroll
        for (int j = 0; j < 16; j += 4) {
            float4 v = *reinterpret_cast<const float4*>(src + j);
            tile[row][c0 + j + 0] = v.x;
            tile[row][c0 + j + 1] = v.y;
            tile[row][c0 + j + 2] = v.z;
            tile[row][c0 + j + 3] = v.w;
        }
        __syncthreads();

        int d  = t >> 2;
        int sc = (t & 3) * 16;
        half8 h0, h1;
#pragma unroll
        for (int j = 0; j < 8; ++j) {
            h0[j] = (_Float16)tile[sc + j][d];
            h1[j] = (_Float16)tile[sc + 8 + j][d];
        }
        _Float16* dst = Vt + ((size_t)(bh * D_HEAD + d)) * T_DIM + s0 + sc;
        *reinterpret_cast<half8*>(dst)     = h0;
        *reinterpret_cast<half8*>(dst + 8) = h1;
    } else {
        int stride = CAST_BLOCKS * 256;
        for (int i = (blockIdx.x - TP_BLOCKS) * 256 + t; i < ntot4; i += stride) {
            const float* src = (i < nk4) ? kin : win;
            _Float16* dst    = (i < nk4) ? Kh  : Wh;
            int j            = (i < nk4) ? i   : i - nk4;
            float4 v = reinterpret_cast<const float4*>(src)[j];
            half4v hh;
            hh[0] = (_Float16)v.x; hh[1] = (_Float16)v.y;
            hh[2] = (_Float16)v.z; hh[3] = (_Float16)v.w;
            reinterpret_cast<half4v*>(dst)[j] = hh;
        }
    }
}

// ---------------------------------------------------------------------------
// 64x64 f16 LDS tile staging (16B-chunk XOR swizzle, inverse-swizzled source)
// ---------------------------------------------------------------------------
__device__ __forceinline__ void stage_gl(const _Float16* __restrict__ g,
                                         size_t stride, _Float16* lds,
                                         int w, int lane) {
    int r0 = lane >> 3;
    int c  = (lane & 7) ^ r0;
#pragma unroll
    for (int j = 0; j < 2; ++j) {
        int r = (w + 4 * j) * 8 + r0;
        const _Float16* src = g + (size_t)r * stride + c * 8;
        _Float16* dst = lds + (w + 4 * j) * 512;   // wave-uniform base
        __builtin_amdgcn_global_load_lds((const AS1 void*)src, (AS3 void*)dst,
                                         16, 0, 0);
    }
}

__device__ __forceinline__ half8 read_frag64(const _Float16* lds, int row, int chunk) {
    int csw = chunk ^ (row & 7);
    return *reinterpret_cast<const half8*>(lds + row * 64 + csw * 8);
}

// Q B-fragment loader: B[k=(lg+4ks)*8+i][col=q=l15], pre-scaled by log2e/8
__device__ __forceinline__ void load_qfrag(const float* qsrc, int lg, half8* qf) {
#pragma unroll
    for (int ks = 0; ks < 2; ++ks) {
        float4 a0 = *reinterpret_cast<const float4*>(qsrc + (lg + 4 * ks) * 8);
        float4 a1 = *reinterpret_cast<const float4*>(qsrc + (lg + 4 * ks) * 8 + 4);
        qf[ks][0] = (_Float16)(a0.x * QSCALE); qf[ks][1] = (_Float16)(a0.y * QSCALE);
        qf[ks][2] = (_Float16)(a0.z * QSCALE); qf[ks][3] = (_Float16)(a0.w * QSCALE);
        qf[ks][4] = (_Float16)(a1.x * QSCALE); qf[ks][5] = (_Float16)(a1.y * QSCALE);
        qf[ks][6] = (_Float16)(a1.z * QSCALE); qf[ks][7] = (_Float16)(a1.w * QSCALE);
    }
}

// ---------------------------------------------------------------------------
// Fused attention, 3-sweep pipeline (round-9 structure) + round-12 tech:
//   sweep 1: P1(A)          — rotated double-tile phases, setprio
//   sweep 2: P2(A) + P1(B)  — P1(B)'s MFMA/exp ride under P2(A)'s stores
//   sweep 3: P2(B)
// Block = 4 waves, 128 q-rows (halves A/B), 512 blocks. One K-staging sweep
// deleted vs 2-pass; read-phase work overlaps the write stream machine-wide.
// Rotation: phys tile = (t + rot) & 31 de-phases resident blocks (anti-convoy).
// LDS-staged K/V, counted-vmcnt FIFO barriers, plain cacheable stores,
// XCD swizzle (4 bh per XCD).
// Operand-swapped QK^T: lane (l15,lg) holds S[q=l15][s=ct*16+lg*4+r].
// ---------------------------------------------------------------------------
__global__ __launch_bounds__(256) void attn_kernel(
        const float* __restrict__ Q, const _Float16* __restrict__ Kh,
        const _Float16* __restrict__ Vt, float* __restrict__ attn_out,
        _Float16* __restrict__ head_h) {
    __shared__ __align__(16) _Float16 kbuf[2][64 * 64];
    __shared__ __align__(16) _Float16 vbuf[2][64 * 64];
    __shared__ __align__(16) _Float16 pbuf[4][16 * 64];

    int tid  = threadIdx.x;
    int wq   = tid >> 6;
    int lane = tid & 63;
    int l15  = lane & 15;
    int lg   = lane >> 4;

    // XCD swizzle: 512 blocks; xcd = flat&7 hosts bh {4*xcd .. 4*xcd+3}.
    int flat = blockIdx.x;
    int i    = flat >> 3;              // 0..63
    int bh   = (flat & 7) * 4 + (i >> 4);
    int qt   = i & 15;
    int q0   = qt * 128;
    int rot  = i & 31;                 // anti-convoy rotation
    int rot2 = rot & 30;               // even: keeps pass-1 pairs aligned
    int b = bh >> 4, h = bh & 15;

    half8 qfA[2], qfB[2];
    load_qfrag(Q + ((size_t)(b * T_DIM + q0 + wq * 16 + l15)) * E_DIM + h * D_HEAD, lg, qfA);
    load_qfrag(Q + ((size_t)(b * T_DIM + q0 + 64 + wq * 16 + l15)) * E_DIM + h * D_HEAD, lg, qfB);

    const _Float16* kg = Kh + ((size_t)b * T_DIM) * E_DIM + h * D_HEAD;
    const _Float16* vg = Vt + (size_t)bh * D_HEAD * T_DIM;

#define P1TILE(KB, QF, LS)                                                     \
    {                                                                          \
        f32x4 acc[4];                                                          \
        _Pragma("unroll")                                                      \
        for (int ct = 0; ct < 4; ++ct) acc[ct] = (f32x4){0.f, 0.f, 0.f, 0.f};  \
        __builtin_amdgcn_s_setprio(1);                                         \
        _Pragma("unroll")                                                      \
        for (int ks = 0; ks < 2; ++ks)                                         \
            _Pragma("unroll")                                                  \
            for (int ct = 0; ct < 4; ++ct) {                                   \
                half8 kf = read_frag64((KB), ct * 16 + l15, lg + 4 * ks);      \
                acc[ct] = __builtin_amdgcn_mfma_f32_16x16x32_f16(              \
                    kf, (QF)[ks], acc[ct], 0, 0, 0);                           \
            }                                                                  \
        __builtin_amdgcn_s_setprio(0);                                         \
        _Pragma("unroll")                                                      \
        for (int ct = 0; ct < 4; ++ct)                                         \
            _Pragma("unroll")                                                  \
            for (int r = 0; r < 4; ++r)                                        \
                (LS) += __builtin_amdgcn_exp2f(acc[ct][r]);                    \
    }

    // QK^T + normalized-P store (global + pbuf) for one tile
#define P2HEAD(KB, QF, RL, ABROW)                                              \
    {                                                                          \
        f32x4 acc[4];                                                          \
        _Pragma("unroll")                                                      \
        for (int ct = 0; ct < 4; ++ct) acc[ct] = (f32x4){0.f, 0.f, 0.f, 0.f};  \
        __builtin_amdgcn_s_setprio(1);                                         \
        _Pragma("unroll")                                                      \
        for (int ks = 0; ks < 2; ++ks)                                         \
            _Pragma("unroll")                                                  \
            for (int ct = 0; ct < 4; ++ct) {                                   \
                half8 kf = read_frag64((KB), ct * 16 + l15, lg + 4 * ks);      \
                acc[ct] = __builtin_amdgcn_mfma_f32_16x16x32_f16(              \
                    kf, (QF)[ks], acc[ct], 0, 0, 0);                           \
            }                                                                  \
        __builtin_amdgcn_s_setprio(0);                                         \
        _Pragma("unroll")                                                      \
        for (int ct = 0; ct < 4; ++ct) {                                       \
            f32x4 p;                                                           \
            p[0] = __builtin_amdgcn_exp2f(acc[ct][0]) * (RL);                  \
            p[1] = __builtin_amdgcn_exp2f(acc[ct][1]) * (RL);                  \
            p[2] = __builtin_amdgcn_exp2f(acc[ct][2]) * (RL);                  \
            p[3] = __builtin_amdgcn_exp2f(acc[ct][3]) * (RL);                  \
            *reinterpret_cast<f32x4*>((ABROW) + ct * 16) = p;                  \
            half4v ph;                                                         \
            ph[0] = (_Float16)p[0]; ph[1] = (_Float16)p[1];                    \
            ph[2] = (_Float16)p[2]; ph[3] = (_Float16)p[3];                    \
            int cc = (ct * 4 + lg) ^ l15;                                      \
            *reinterpret_cast<half4v*>(pw + l15 * 64 + cc * 4) = ph;           \
        }                                                                      \
    }

#define PVTILE(VB)                                                             \
    {                                                                          \
        __builtin_amdgcn_s_setprio(1);                                         \
        _Pragma("unroll")                                                      \
        for (int ks = 0; ks < 2; ++ks) {                                       \
            int c0 = 2 * (lg + 4 * ks);                                        \
            half4v lo = *reinterpret_cast<const half4v*>(                      \
                pw + l15 * 64 + ((c0)     ^ l15) * 4);                         \
            half4v hi = *reinterpret_cast<const half4v*>(                      \
                pw + l15 * 64 + ((c0 + 1) ^ l15) * 4);                         \
            half8 pa;                                                          \
            pa[0] = lo[0]; pa[1] = lo[1]; pa[2] = lo[2]; pa[3] = lo[3];        \
            pa[4] = hi[0]; pa[5] = hi[1]; pa[6] = hi[2]; pa[7] = hi[3];        \
            _Pragma("unroll")                                                  \
            for (int cd = 0; cd < 4; ++cd) {                                   \
                half8 vf = read_frag64((VB), cd * 16 + l15, lg + 4 * ks);      \
                oacc[cd] = __builtin_amdgcn_mfma_f32_16x16x32_f16(             \
                    pa, vf, oacc[cd], 0, 0, 0);                                \
            }                                                                  \
        }                                                                      \
        __builtin_amdgcn_s_setprio(0);                                         \
    }

    float* ab = attn_out + (size_t)bh * T_DIM * T_DIM;
    _Float16* pw = pbuf[wq];
    int myqA = q0 + wq * 16 + l15;
    int myqB = myqA + 64;

    // ---------------- sweep 1: P1(A), rotated double-tile phases ----------
#define IDX1(n) (((n) + rot2) & 31)
    float lsumA = 0.0f, lsumB = 0.0f;
    stage_gl(kg + (size_t)IDX1(0) * 64 * E_DIM, E_DIM, kbuf[0], wq, lane);
    stage_gl(kg + (size_t)IDX1(1) * 64 * E_DIM, E_DIM, kbuf[1], wq, lane);
    for (int tt = 0; tt < NT / 2; tt += 2) {
        {
            stage_gl(kg + (size_t)IDX1(2 * tt + 2) * 64 * E_DIM, E_DIM, vbuf[0], wq, lane);
            stage_gl(kg + (size_t)IDX1(2 * tt + 3) * 64 * E_DIM, E_DIM, vbuf[1], wq, lane);
            BAR_VM(4);
            P1TILE(kbuf[0], qfA, lsumA);
            P1TILE(kbuf[1], qfA, lsumA);
            bar_plain();
        }
        {
            if (tt + 2 < NT / 2) {
                stage_gl(kg + (size_t)IDX1(2 * tt + 4) * 64 * E_DIM, E_DIM, kbuf[0], wq, lane);
                stage_gl(kg + (size_t)IDX1(2 * tt + 5) * 64 * E_DIM, E_DIM, kbuf[1], wq, lane);
                BAR_VM(4);
            } else {
                BAR_VM(0);
            }
            P1TILE(vbuf[0], qfA, lsumA);
            P1TILE(vbuf[1], qfA, lsumA);
            bar_plain();
        }
    }
#undef IDX1

    lsumA += __shfl_xor(lsumA, 16);
    lsumA += __shfl_xor(lsumA, 32);
    float rlA = 1.0f / lsumA;

    f32x4 oacc[4];
#pragma unroll
    for (int cd = 0; cd < 4; ++cd) oacc[cd] = (f32x4){0.f, 0.f, 0.f, 0.f};

    bar_plain();   // sweep-1 buffer reads done before sweep-2 staging

    // ---------------- sweep 2: P2(A) + P1(B), rotated ----------------
    // FIFO per tile: stage(t)=4 (K2+V2), stores(t)=4. After stage(t):
    // t==0 -> stage(1)=4; steady -> stores(t-1)+stage(t+1)=8; last -> 4.
    int cur = 0;
    {
        int p0 = rot;
        stage_gl(kg + (size_t)p0 * 64 * E_DIM, E_DIM, kbuf[0], wq, lane);
        stage_gl(vg + p0 * 64, T_DIM, vbuf[0], wq, lane);
    }
    for (int t = 0; t < NT; ++t) {
        int phys = (t + rot) & 31;
        if (t < NT - 1) {
            int pn = (t + 1 + rot) & 31;
            stage_gl(kg + (size_t)pn * 64 * E_DIM, E_DIM, kbuf[cur ^ 1], wq, lane);
            stage_gl(vg + pn * 64, T_DIM, vbuf[cur ^ 1], wq, lane);
        }
        if (t == 0)           BAR_VM(4);
        else if (t < NT - 1)  BAR_VM(8);
        else                  BAR_VM(4);
        const _Float16* kb = kbuf[cur];
        const _Float16* vb = vbuf[cur];

        float* abrowA = ab + (size_t)myqA * T_DIM + phys * 64 + lg * 4;
        P2HEAD(kb, qfA, rlA, abrowA);        // QK(A) + stores(A) + pbuf
        P1TILE(kb, qfB, lsumB);              // QK(B) sums ride under stores
        PVTILE(vb);                          // PV(A)
        bar_plain();
        cur ^= 1;
    }

    lsumB += __shfl_xor(lsumB, 16);
    lsumB += __shfl_xor(lsumB, 32);
    float rlB = 1.0f / lsumB;

    // head(A) -> workspace [B*T][E]; O[q=lg*4+r][d=cd*16+l15]
    {
        _Float16* hw = head_h + ((size_t)(b * T_DIM + q0 + wq * 16)) * E_DIM + h * D_HEAD;
#pragma unroll
        for (int cd = 0; cd < 4; ++cd)
#pragma unroll
            for (int r = 0; r < 4; ++r)
                hw[(size_t)(lg * 4 + r) * E_DIM + cd * 16 + l15] = (_Float16)oacc[cd][r];
    }

#pragma unroll
    for (int cd = 0; cd < 4; ++cd) oacc[cd] = (f32x4){0.f, 0.f, 0.f, 0.f};

    // ---------------- sweep 3: P2(B), rotated ----------------
    // t==0: FIFO = stores(s2:30,31)=8 + stage(0)=4 + stage(1)=4; waiting to
    // N=4 retires the trailing sweep-2 stores AND stage(0): correct.
    cur = 0;
    {
        int p0 = rot;
        stage_gl(kg + (size_t)p0 * 64 * E_DIM, E_DIM, kbuf[0], wq, lane);
        stage_gl(vg + p0 * 64, T_DIM, vbuf[0], wq, lane);
    }
    for (int t = 0; t < NT; ++t) {
        int phys = (t + rot) & 31;
        if (t < NT - 1) {
            int pn = (t + 1 + rot) & 31;
            stage_gl(kg + (size_t)pn * 64 * E_DIM, E_DIM, kbuf[cur ^ 1], wq, lane);
            stage_gl(vg + pn * 64, T_DIM, vbuf[cur ^ 1], wq, lane);
        }
        if (t == 0)           BAR_VM(4);
        else if (t < NT - 1)  BAR_VM(8);
        else                  BAR_VM(4);
        const _Float16* kb = kbuf[cur];
        const _Float16* vb = vbuf[cur];

        float* abrowB = ab + (size_t)myqB * T_DIM + phys * 64 + lg * 4;
        P2HEAD(kb, qfB, rlB, abrowB);
        PVTILE(vb);
        bar_plain();
        cur ^= 1;
    }

    // head(B)
    {
        _Float16* hw = head_h + ((size_t)(b * T_DIM + q0 + 64 + wq * 16)) * E_DIM + h * D_HEAD;
#pragma unroll
        for (int cd = 0; cd < 4; ++cd)
#pragma unroll
            for (int r = 0; r < 4; ++r)
                hw[(size_t)(lg * 4 + r) * E_DIM + cd * 16 + l15] = (_Float16)oacc[cd][r];
    }
#undef P1TILE
#undef P2HEAD
#undef PVTILE
}

// ---------------------------------------------------------------------------
// outputs[m][n] = sum_k head[m][k]*W[n][k]  (M=4096,N=1024,K=1024)
// Operand-swapped: acc = mfma(A=W_frag, B=head_frag) -> dwordx4 C stores.
// ---------------------------------------------------------------------------
__global__ __launch_bounds__(256) void proj_kernel(
        const _Float16* __restrict__ A, const _Float16* __restrict__ Wh,
        float* __restrict__ out) {
    __shared__ __align__(16) _Float16 abuf[2][64 * 64];
    __shared__ __align__(16) _Float16 bbuf[2][64 * 64];

    int tid  = threadIdx.x;
    int wq   = tid >> 6;
    int lane = tid & 63;
    int l15  = lane & 15;
    int lg   = lane >> 4;

    int m0 = blockIdx.x * 64;
    int n0 = blockIdx.y * 64;

    f32x4 acc[4];
#pragma unroll
    for (int ct = 0; ct < 4; ++ct) acc[ct] = (f32x4){0.f, 0.f, 0.f, 0.f};

    int cur = 0;
    stage_gl(A  + (size_t)m0 * E_DIM, E_DIM, abuf[0], wq, lane);
    stage_gl(Wh + (size_t)n0 * E_DIM, E_DIM, bbuf[0], wq, lane);
    for (int t = 0; t < E_DIM / 64; ++t) {
        if (t + 1 < E_DIM / 64) {
            stage_gl(A  + (size_t)m0 * E_DIM + (t + 1) * 64, E_DIM, abuf[cur ^ 1], wq, lane);
            stage_gl(Wh + (size_t)n0 * E_DIM + (t + 1) * 64, E_DIM, bbuf[cur ^ 1], wq, lane);
            BAR_VM(4);
        } else {
            BAR_VM(0);
        }
#pragma unroll
        for (int ks = 0; ks < 2; ++ks) {
            half8 hf = read_frag64(abuf[cur], wq * 16 + l15, lg + 4 * ks);
#pragma unroll
            for (int ct = 0; ct < 4; ++ct) {
                half8 wf = read_frag64(bbuf[cur], ct * 16 + l15, lg + 4 * ks);
                acc[ct] = __builtin_amdgcn_mfma_f32_16x16x32_f16(wf, hf, acc[ct], 0, 0, 0);
            }
        }
        bar_plain();
        cur ^= 1;
    }

    float* orow = out + (size_t)(m0 + wq * 16 + l15) * E_DIM + n0 + lg * 4;
#pragma unroll
    for (int ct = 0; ct < 4; ++ct) {
        f32x4 o;
        o[0] = acc[ct][0]; o[1] = acc[ct][1]; o[2] = acc[ct][2]; o[3] = acc[ct][3];
        *reinterpret_cast<f32x4*>(orow + ct * 16) = o;
    }
}

// ---------------------------------------------------------------------------
extern "C" void kernel_launch(void* const* d_in, const int* in_sizes, int n_in,
                              void* d_out, int out_size, void* d_ws, size_t ws_size,
                              hipStream_t stream) {
    const float* q = (const float*)d_in[0];
    const float* k = (const float*)d_in[1];
    const float* v = (const float*)d_in[2];
    const float* w = (const float*)d_in[3];

    float* outs = (float*)d_out;
    float* attn = outs + (size_t)B_NUM * T_DIM * E_DIM;   // [32,2048,2048]

    char* ws = (char*)d_ws;
    _Float16* Kh = (_Float16*)(ws);                       //  8 MiB @ 0
    _Float16* Vt = (_Float16*)(ws + (size_t)(8  << 20));  //  8 MiB
    _Float16* Wh = (_Float16*)(ws + (size_t)(16 << 20));  //  2 MiB
    _Float16* Hh = (_Float16*)(ws + (size_t)(18 << 20));  //  8 MiB

    int nk4 = B_NUM * T_DIM * E_DIM / 4;     // 1,048,576
    int nw4 = E_DIM * E_DIM / 4;             //   262,144

    prep_kernel<<<TP_BLOCKS + CAST_BLOCKS, 256, 0, stream>>>(
        k, w, v, Kh, Wh, Vt, nk4, nk4 + nw4);
    attn_kernel<<<(T_DIM / 128) * BH_NUM, 256, 0, stream>>>(q, Kh, Vt, attn, Hh);
    proj_kernel<<<dim3((B_NUM * T_DIM) / 64, E_DIM / 64), 256, 0, stream>>>(Hh, Wh, outs);
}

// Round 14
// 187.206 us; speedup vs baseline: 1.0890x; 1.0890x over previous
//
#include <hip/hip_runtime.h>
#include <hip/hip_fp16.h>

// Problem constants (fixed by the reference): B=2, T=2048, E=1024, H=16, d=64
#define B_NUM  2
#define T_DIM  2048
#define E_DIM  1024
#define H_NUM  16
#define D_HEAD 64
#define BH_NUM (B_NUM * H_NUM)
#define NT     (T_DIM / 64)

using half8  = __attribute__((ext_vector_type(8))) _Float16;
using half4v = __attribute__((ext_vector_type(4))) _Float16;
using f32x4  = __attribute__((ext_vector_type(4))) float;

#define AS1 __attribute__((address_space(1)))
#define AS3 __attribute__((address_space(3)))

// 1/sqrt(64) * log2(e): MFMA yields S*log2e, so v_exp_f32 (2^x) == exp(S)
#define QSCALE 0.18033688011112042f

// Barrier with counted vmcnt: retire the target stage (N = 2 x number of
// stage ops issued after it), then sync. sched_barrier stops the compiler
// hoisting LDS reads above the wait (rule #18).
#define BAR_VM(N)                                                       \
    do {                                                                \
        asm volatile("s_waitcnt vmcnt(" #N ")" ::: "memory");           \
        __builtin_amdgcn_s_barrier();                                   \
        __builtin_amdgcn_sched_barrier(0);                              \
    } while (0)

// End-of-tile barrier (no counter drain).
__device__ __forceinline__ void bar_plain() {
    __builtin_amdgcn_s_barrier();
    __builtin_amdgcn_sched_barrier(0);
}

// ---------------------------------------------------------------------------
// merged prep: blocks [0,1024) transpose V -> Vt; blocks [1024,2304) cast
// K and W to f16 (grid-stride).
// ---------------------------------------------------------------------------
#define TP_BLOCKS  (NT * BH_NUM)          // 1024
#define CAST_BLOCKS 1280
__global__ void prep_kernel(const float* __restrict__ kin,
                            const float* __restrict__ win,
                            const float* __restrict__ V,
                            _Float16* __restrict__ Kh,
                            _Float16* __restrict__ Wh,
                            _Float16* __restrict__ Vt,
                            int nk4, int ntot4) {
    __shared__ float tile[64][65];
    int t = threadIdx.x;

    if (blockIdx.x < TP_BLOCKS) {
        int s0 = (blockIdx.x & 31) * 64;
        int bh = blockIdx.x >> 5;
        int b = bh >> 4, h = bh & 15;

        int row = t >> 2;
        int c0  = (t & 3) * 16;
        const float* src = V + ((size_t)(b * T_DIM + s0 + row)) * E_DIM + h * D_HEAD + c0;
#pragma unroll
        for (int j = 0; j < 16; j += 4) {
            float4 v = *reinterpret_cast<const float4*>(src + j);
            tile[row][c0 + j + 0] = v.x;
            tile[row][c0 + j + 1] = v.y;
            tile[row][c0 + j + 2] = v.z;
            tile[row][c0 + j + 3] = v.w;
        }
        __syncthreads();

        int d  = t >> 2;
        int sc = (t & 3) * 16;
        half8 h0, h1;
#pragma unroll
        for (int j = 0; j < 8; ++j) {
            h0[j] = (_Float16)tile[sc + j][d];
            h1[j] = (_Float16)tile[sc + 8 + j][d];
        }
        _Float16* dst = Vt + ((size_t)(bh * D_HEAD + d)) * T_DIM + s0 + sc;
        *reinterpret_cast<half8*>(dst)     = h0;
        *reinterpret_cast<half8*>(dst + 8) = h1;
    } else {
        int stride = CAST_BLOCKS * 256;
        for (int i = (blockIdx.x - TP_BLOCKS) * 256 + t; i < ntot4; i += stride) {
            const float* src = (i < nk4) ? kin : win;
            _Float16* dst    = (i < nk4) ? Kh  : Wh;
            int j            = (i < nk4) ? i   : i - nk4;
            float4 v = reinterpret_cast<const float4*>(src)[j];
            half4v hh;
            hh[0] = (_Float16)v.x; hh[1] = (_Float16)v.y;
            hh[2] = (_Float16)v.z; hh[3] = (_Float16)v.w;
            reinterpret_cast<half4v*>(dst)[j] = hh;
        }
    }
}

// ---------------------------------------------------------------------------
// 64x64 f16 LDS tile staging (16B-chunk XOR swizzle, inverse-swizzled source)
// ---------------------------------------------------------------------------
__device__ __forceinline__ void stage_gl(const _Float16* __restrict__ g,
                                         size_t stride, _Float16* lds,
                                         int w, int lane) {
    int r0 = lane >> 3;
    int c  = (lane & 7) ^ r0;
#pragma unroll
    for (int j = 0; j < 2; ++j) {
        int r = (w + 4 * j) * 8 + r0;
        const _Float16* src = g + (size_t)r * stride + c * 8;
        _Float16* dst = lds + (w + 4 * j) * 512;   // wave-uniform base
        __builtin_amdgcn_global_load_lds((const AS1 void*)src, (AS3 void*)dst,
                                         16, 0, 0);
    }
}

__device__ __forceinline__ half8 read_frag64(const _Float16* lds, int row, int chunk) {
    int csw = chunk ^ (row & 7);
    return *reinterpret_cast<const half8*>(lds + row * 64 + csw * 8);
}

// Q B-fragment loader: B[k=(lg+4ks)*8+i][col=q=l15], pre-scaled by log2e/8
__device__ __forceinline__ void load_qfrag(const float* qsrc, int lg, half8* qf) {
#pragma unroll
    for (int ks = 0; ks < 2; ++ks) {
        float4 a0 = *reinterpret_cast<const float4*>(qsrc + (lg + 4 * ks) * 8);
        float4 a1 = *reinterpret_cast<const float4*>(qsrc + (lg + 4 * ks) * 8 + 4);
        qf[ks][0] = (_Float16)(a0.x * QSCALE); qf[ks][1] = (_Float16)(a0.y * QSCALE);
        qf[ks][2] = (_Float16)(a0.z * QSCALE); qf[ks][3] = (_Float16)(a0.w * QSCALE);
        qf[ks][4] = (_Float16)(a1.x * QSCALE); qf[ks][5] = (_Float16)(a1.y * QSCALE);
        qf[ks][6] = (_Float16)(a1.z * QSCALE); qf[ks][7] = (_Float16)(a1.w * QSCALE);
    }
}

// ---------------------------------------------------------------------------
// Fused attention (round-12 chassis) + DEPTH-3 pass-1 pipeline:
// 5 LDS tile slots (kbuf0,kbuf1,vbuf0,vbuf1,pbuf — pbuf is idle in pass 1).
// Pass 1: single-tile phases, stage issued 3 phases ahead, ONE barrier per
// phase (safe at depth>=2: stage(t+3) overwriting slot(t-2) is separated
// from all waves' compute(t-2) by phase t-1's barrier; slots distinct mod 5).
// Steady BAR_VM(6); tail 4/2/0. Rotation (t+qt)&31 de-phases blocks.
// Pass 2: unchanged round-12 (K/V dbuf, stores ride 2 tiles, BAR_VM(8)).
// Plain cacheable stores, XCD swizzle, setprio around MFMA clusters.
// Operand-swapped QK^T: lane (l15,lg) holds S[q=l15][s=ct*16+lg*4+r].
// ---------------------------------------------------------------------------
__global__ __launch_bounds__(256) void attn_kernel(
        const float* __restrict__ Q, const _Float16* __restrict__ Kh,
        const _Float16* __restrict__ Vt, float* __restrict__ attn_out,
        _Float16* __restrict__ head_h) {
    __shared__ __align__(16) _Float16 smem[5 * 4096];   // 5 tile slots, 40 KB
#define SLOTP(s) (smem + (s) * 4096)

    int tid  = threadIdx.x;
    int wq   = tid >> 6;
    int lane = tid & 63;
    int l15  = lane & 15;
    int lg   = lane >> 4;

    // XCD swizzle: xcd = flat&7 hosts bh {4*xcd .. 4*xcd+3}; qt = (flat>>3)&31
    int flat = blockIdx.x;
    int bh   = (flat & 7) * 4 + (flat >> 8);
    int qt   = (flat >> 3) & 31;
    int q0   = qt * 64;
    int b = bh >> 4, h = bh & 15;

    const float* qsrc = Q + ((size_t)(b * T_DIM + q0 + wq * 16 + l15)) * E_DIM + h * D_HEAD;
    half8 qfrag[2];
    load_qfrag(qsrc, lg, qfrag);

    const _Float16* kg = Kh + ((size_t)b * T_DIM) * E_DIM + h * D_HEAD;
    const _Float16* vg = Vt + (size_t)bh * D_HEAD * T_DIM;

#define P1TILE(KB)                                                             \
    {                                                                          \
        f32x4 acc[4];                                                          \
        _Pragma("unroll")                                                      \
        for (int ct = 0; ct < 4; ++ct) acc[ct] = (f32x4){0.f, 0.f, 0.f, 0.f};  \
        __builtin_amdgcn_s_setprio(1);                                         \
        _Pragma("unroll")                                                      \
        for (int ks = 0; ks < 2; ++ks)                                         \
            _Pragma("unroll")                                                  \
            for (int ct = 0; ct < 4; ++ct) {                                   \
                half8 kf = read_frag64((KB), ct * 16 + l15, lg + 4 * ks);      \
                acc[ct] = __builtin_amdgcn_mfma_f32_16x16x32_f16(              \
                    kf, qfrag[ks], acc[ct], 0, 0, 0);                          \
            }                                                                  \
        __builtin_amdgcn_s_setprio(0);                                         \
        _Pragma("unroll")                                                      \
        for (int ct = 0; ct < 4; ++ct)                                         \
            _Pragma("unroll")                                                  \
            for (int r = 0; r < 4; ++r)                                        \
                lsum += __builtin_amdgcn_exp2f(acc[ct][r]);                    \
    }

#define SLOTSEL(s) ((s) == 0 ? SLOTP(0) : (s) == 1 ? SLOTP(1) :                \
                    (s) == 2 ? SLOTP(2) : (s) == 3 ? SLOTP(3) : SLOTP(4))

    // ---------------- pass 1: depth-3 single-barrier pipeline ----------------
    float lsum = 0.0f;
    {
#define IDX1(n) (((n) + qt) & 31)
        stage_gl(kg + (size_t)IDX1(0) * 64 * E_DIM, E_DIM, SLOTP(0), wq, lane);
        stage_gl(kg + (size_t)IDX1(1) * 64 * E_DIM, E_DIM, SLOTP(1), wq, lane);
        stage_gl(kg + (size_t)IDX1(2) * 64 * E_DIM, E_DIM, SLOTP(2), wq, lane);
        int ss = 3, sc = 0;
        for (int t = 0; t <= NT - 4; ++t) {
            _Float16* sp = SLOTSEL(ss);
            stage_gl(kg + (size_t)IDX1(t + 3) * 64 * E_DIM, E_DIM, sp, wq, lane);
            BAR_VM(6);                 // retire stage(t); t+1..t+3 in flight
            const _Float16* cp = SLOTSEL(sc);
            P1TILE(cp);
            ss = (ss == 4) ? 0 : ss + 1;
            sc = (sc == 4) ? 0 : sc + 1;
        }
        // peeled tail: t = NT-3, NT-2, NT-1 (no further stages)
        BAR_VM(4);
        { const _Float16* cp = SLOTSEL(sc); P1TILE(cp); }
        sc = (sc == 4) ? 0 : sc + 1;
        BAR_VM(2);
        { const _Float16* cp = SLOTSEL(sc); P1TILE(cp); }
        sc = (sc == 4) ? 0 : sc + 1;
        BAR_VM(0);
        { const _Float16* cp = SLOTSEL(sc); P1TILE(cp); }
#undef IDX1
    }

    // reduce across the 4 lg replicas of each q row
    lsum += __shfl_xor(lsum, 16);
    lsum += __shfl_xor(lsum, 32);
    float rl = 1.0f / lsum;

    f32x4 oacc[4];
#pragma unroll
    for (int cd = 0; cd < 4; ++cd) oacc[cd] = (f32x4){0.f, 0.f, 0.f, 0.f};

    float* ab = attn_out + (size_t)bh * T_DIM * T_DIM;
    _Float16* pw = SLOTP(4) + wq * 1024;    // pbuf = slot 4 (idle in pass 1)
    int myq = q0 + wq * 16 + l15;

    // boundary: all waves done with pass-1 slot reads before pass-2 staging
    bar_plain();

    // ---------------- pass 2: P write + PV (round-12, rotated) --------------
    // kbuf[cur] = SLOTP(cur), vbuf[cur] = SLOTP(2+cur).
    // FIFO per tile: stage(t)=4 (K2+V2), stores(t)=4. After stage(t):
    // t==0 -> stage(1)=4; steady -> stores(t-1)+stage(t+1)=8; last -> 4.
    int cur = 0;
    {
        int p0 = qt & 31;
        stage_gl(kg + (size_t)p0 * 64 * E_DIM, E_DIM, SLOTP(0), wq, lane);
        stage_gl(vg + p0 * 64, T_DIM, SLOTP(2), wq, lane);
    }
    for (int t = 0; t < NT; ++t) {
        int phys = (t + qt) & 31;
        if (t < NT - 1) {
            int pn = (t + 1 + qt) & 31;
            _Float16* kn = cur ? SLOTP(0) : SLOTP(1);
            _Float16* vn = cur ? SLOTP(2) : SLOTP(3);
            stage_gl(kg + (size_t)pn * 64 * E_DIM, E_DIM, kn, wq, lane);
            stage_gl(vg + pn * 64, T_DIM, vn, wq, lane);
        }
        if (t == 0)           BAR_VM(4);
        else if (t < NT - 1)  BAR_VM(8);   // P-stores ride 2 tiles in flight
        else                  BAR_VM(4);
        const _Float16* kb = cur ? SLOTP(1) : SLOTP(0);
        const _Float16* vb = cur ? SLOTP(3) : SLOTP(2);

        f32x4 acc[4];
#pragma unroll
        for (int ct = 0; ct < 4; ++ct) acc[ct] = (f32x4){0.f, 0.f, 0.f, 0.f};
        __builtin_amdgcn_s_setprio(1);
#pragma unroll
        for (int ks = 0; ks < 2; ++ks)
#pragma unroll
            for (int ct = 0; ct < 4; ++ct) {
                half8 kf = read_frag64(kb, ct * 16 + l15, lg + 4 * ks);
                acc[ct] = __builtin_amdgcn_mfma_f32_16x16x32_f16(kf, qfrag[ks], acc[ct], 0, 0, 0);
            }
        __builtin_amdgcn_s_setprio(0);

        // P: one plain dwordx4 global store (L2 write-combined) + b64 pbuf
        float* abrow = ab + (size_t)myq * T_DIM + phys * 64 + lg * 4;
#pragma unroll
        for (int ct = 0; ct < 4; ++ct) {
            f32x4 p;
            p[0] = __builtin_amdgcn_exp2f(acc[ct][0]) * rl;
            p[1] = __builtin_amdgcn_exp2f(acc[ct][1]) * rl;
            p[2] = __builtin_amdgcn_exp2f(acc[ct][2]) * rl;
            p[3] = __builtin_amdgcn_exp2f(acc[ct][3]) * rl;
            *reinterpret_cast<f32x4*>(abrow + ct * 16) = p;
            half4v ph;
            ph[0] = (_Float16)p[0]; ph[1] = (_Float16)p[1];
            ph[2] = (_Float16)p[2]; ph[3] = (_Float16)p[3];
            int cc = (ct * 4 + lg) ^ l15;          // 4-bit XOR: bank-balanced
            *reinterpret_cast<half4v*>(pw + l15 * 64 + cc * 4) = ph;
        }

        // PV: A = P[q=l15][s], B = V[s][d] (vbuf rows are d from Vt)
        __builtin_amdgcn_s_setprio(1);
#pragma unroll
        for (int ks = 0; ks < 2; ++ks) {
            int c0 = 2 * (lg + 4 * ks);
            half4v lo = *reinterpret_cast<const half4v*>(pw + l15 * 64 + ((c0)     ^ l15) * 4);
            half4v hi = *reinterpret_cast<const half4v*>(pw + l15 * 64 + ((c0 + 1) ^ l15) * 4);
            half8 pa;
            pa[0] = lo[0]; pa[1] = lo[1]; pa[2] = lo[2]; pa[3] = lo[3];
            pa[4] = hi[0]; pa[5] = hi[1]; pa[6] = hi[2]; pa[7] = hi[3];
#pragma unroll
            for (int cd = 0; cd < 4; ++cd) {
                half8 vf = read_frag64(vb, cd * 16 + l15, lg + 4 * ks);
                oacc[cd] = __builtin_amdgcn_mfma_f32_16x16x32_f16(pa, vf, oacc[cd], 0, 0, 0);
            }
        }
        __builtin_amdgcn_s_setprio(0);
        bar_plain();                   // buf[cur] reads done; next overwrite ok
        cur ^= 1;
    }

    // head (f16) -> workspace [B*T][E]; O[q=lg*4+r][d=cd*16+l15]
    _Float16* hw = head_h + ((size_t)(b * T_DIM + q0 + wq * 16)) * E_DIM + h * D_HEAD;
#pragma unroll
    for (int cd = 0; cd < 4; ++cd)
#pragma unroll
        for (int r = 0; r < 4; ++r) {
            int qm = lg * 4 + r;
            hw[(size_t)qm * E_DIM + cd * 16 + l15] = (_Float16)oacc[cd][r];
        }
#undef P1TILE
#undef SLOTSEL
#undef SLOTP
}

// ---------------------------------------------------------------------------
// outputs[m][n] = sum_k head[m][k]*W[n][k]  (M=4096,N=1024,K=1024)
// Operand-swapped: acc = mfma(A=W_frag, B=head_frag) -> dwordx4 C stores.
// ---------------------------------------------------------------------------
__global__ __launch_bounds__(256) void proj_kernel(
        const _Float16* __restrict__ A, const _Float16* __restrict__ Wh,
        float* __restrict__ out) {
    __shared__ __align__(16) _Float16 abuf[2][64 * 64];
    __shared__ __align__(16) _Float16 bbuf[2][64 * 64];

    int tid  = threadIdx.x;
    int wq   = tid >> 6;
    int lane = tid & 63;
    int l15  = lane & 15;
    int lg   = lane >> 4;

    int m0 = blockIdx.x * 64;
    int n0 = blockIdx.y * 64;

    f32x4 acc[4];
#pragma unroll
    for (int ct = 0; ct < 4; ++ct) acc[ct] = (f32x4){0.f, 0.f, 0.f, 0.f};

    int cur = 0;
    stage_gl(A  + (size_t)m0 * E_DIM, E_DIM, abuf[0], wq, lane);
    stage_gl(Wh + (size_t)n0 * E_DIM, E_DIM, bbuf[0], wq, lane);
    for (int t = 0; t < E_DIM / 64; ++t) {
        if (t + 1 < E_DIM / 64) {
            stage_gl(A  + (size_t)m0 * E_DIM + (t + 1) * 64, E_DIM, abuf[cur ^ 1], wq, lane);
            stage_gl(Wh + (size_t)n0 * E_DIM + (t + 1) * 64, E_DIM, bbuf[cur ^ 1], wq, lane);
            BAR_VM(4);
        } else {
            BAR_VM(0);
        }
#pragma unroll
        for (int ks = 0; ks < 2; ++ks) {
            half8 hf = read_frag64(abuf[cur], wq * 16 + l15, lg + 4 * ks);
#pragma unroll
            for (int ct = 0; ct < 4; ++ct) {
                half8 wf = read_frag64(bbuf[cur], ct * 16 + l15, lg + 4 * ks);
                acc[ct] = __builtin_amdgcn_mfma_f32_16x16x32_f16(wf, hf, acc[ct], 0, 0, 0);
            }
        }
        bar_plain();
        cur ^= 1;
    }

    float* orow = out + (size_t)(m0 + wq * 16 + l15) * E_DIM + n0 + lg * 4;
#pragma unroll
    for (int ct = 0; ct < 4; ++ct) {
        f32x4 o;
        o[0] = acc[ct][0]; o[1] = acc[ct][1]; o[2] = acc[ct][2]; o[3] = acc[ct][3];
        *reinterpret_cast<f32x4*>(orow + ct * 16) = o;
    }
}

// ---------------------------------------------------------------------------
extern "C" void kernel_launch(void* const* d_in, const int* in_sizes, int n_in,
                              void* d_out, int out_size, void* d_ws, size_t ws_size,
                              hipStream_t stream) {
    const float* q = (const float*)d_in[0];
    const float* k = (const float*)d_in[1];
    const float* v = (const float*)d_in[2];
    const float* w = (const float*)d_in[3];

    float* outs = (float*)d_out;
    float* attn = outs + (size_t)B_NUM * T_DIM * E_DIM;   // [32,2048,2048]

    char* ws = (char*)d_ws;
    _Float16* Kh = (_Float16*)(ws);                       //  8 MiB @ 0
    _Float16* Vt = (_Float16*)(ws + (size_t)(8  << 20));  //  8 MiB
    _Float16* Wh = (_Float16*)(ws + (size_t)(16 << 20));  //  2 MiB
    _Float16* Hh = (_Float16*)(ws + (size_t)(18 << 20));  //  8 MiB

    int nk4 = B_NUM * T_DIM * E_DIM / 4;     // 1,048,576
    int nw4 = E_DIM * E_DIM / 4;             //   262,144

    prep_kernel<<<TP_BLOCKS + CAST_BLOCKS, 256, 0, stream>>>(
        k, w, v, Kh, Wh, Vt, nk4, nk4 + nw4);
    attn_kernel<<<NT * BH_NUM, 256, 0, stream>>>(q, Kh, Vt, attn, Hh);
    proj_kernel<<<dim3((B_NUM * T_DIM) / 64, E_DIM / 64), 256, 0, stream>>>(Hh, Wh, outs);
}

// Round 15
// 183.220 us; speedup vs baseline: 1.1127x; 1.0218x over previous
//
#include <hip/hip_runtime.h>
#include <hip/hip_fp16.h>

// Problem constants (fixed by the reference): B=2, T=2048, E=1024, H=16, d=64
#define B_NUM  2
#define T_DIM  2048
#define E_DIM  1024
#define H_NUM  16
#define D_HEAD 64
#define BH_NUM (B_NUM * H_NUM)
#define NT     (T_DIM / 64)

using half8  = __attribute__((ext_vector_type(8))) _Float16;
using half4v = __attribute__((ext_vector_type(4))) _Float16;
using f32x4  = __attribute__((ext_vector_type(4))) float;

#define AS1 __attribute__((address_space(1)))
#define AS3 __attribute__((address_space(3)))

// 1/sqrt(64) * log2(e): MFMA yields S*log2e, so v_exp_f32 (2^x) == exp(S)
#define QSCALE 0.18033688011112042f

// Mid-tile barrier: retire the previous cooperative stage (own-wave count N =
// number of VMEM ops issued AFTER the target stage), then sync so all waves'
// stages are visible. sched_barrier stops the compiler hoisting the LDS
// reads above the wait (rule #18).
#define BAR_VM(N)                                                       \
    do {                                                                \
        asm volatile("s_waitcnt vmcnt(" #N ")" ::: "memory");           \
        __builtin_amdgcn_s_barrier();                                   \
        __builtin_amdgcn_sched_barrier(0);                              \
    } while (0)

// End-of-tile barrier: all waves finished READING the current LDS buffer.
__device__ __forceinline__ void bar_plain() {
    __builtin_amdgcn_s_barrier();
    __builtin_amdgcn_sched_barrier(0);
}

// ---------------------------------------------------------------------------
// merged prep: blocks [0,1024) transpose V -> Vt; blocks [1024,2304) cast
// K and W to f16 (grid-stride). One launch instead of two.
// ---------------------------------------------------------------------------
#define TP_BLOCKS  (NT * BH_NUM)          // 1024
#define CAST_BLOCKS 1280
__global__ void prep_kernel(const float* __restrict__ kin,
                            const float* __restrict__ win,
                            const float* __restrict__ V,
                            _Float16* __restrict__ Kh,
                            _Float16* __restrict__ Wh,
                            _Float16* __restrict__ Vt,
                            int nk4, int ntot4) {
    __shared__ float tile[64][65];
    int t = threadIdx.x;

    if (blockIdx.x < TP_BLOCKS) {
        // ---- transpose V [B,T,E] -> Vt [BH, D_HEAD, T] ----
        int s0 = (blockIdx.x & 31) * 64;
        int bh = blockIdx.x >> 5;
        int b = bh >> 4, h = bh & 15;

        int row = t >> 2;
        int c0  = (t & 3) * 16;
        const float* src = V + ((size_t)(b * T_DIM + s0 + row)) * E_DIM + h * D_HEAD + c0;
#pragma unroll
        for (int j = 0; j < 16; j += 4) {
            float4 v = *reinterpret_cast<const float4*>(src + j);
            tile[row][c0 + j + 0] = v.x;
            tile[row][c0 + j + 1] = v.y;
            tile[row][c0 + j + 2] = v.z;
            tile[row][c0 + j + 3] = v.w;
        }
        __syncthreads();

        int d  = t >> 2;
        int sc = (t & 3) * 16;
        half8 h0, h1;
#pragma unroll
        for (int j = 0; j < 8; ++j) {
            h0[j] = (_Float16)tile[sc + j][d];
            h1[j] = (_Float16)tile[sc + 8 + j][d];
        }
        _Float16* dst = Vt + ((size_t)(bh * D_HEAD + d)) * T_DIM + s0 + sc;
        *reinterpret_cast<half8*>(dst)     = h0;
        *reinterpret_cast<half8*>(dst + 8) = h1;
    } else {
        // ---- cast K then W, f32 -> f16, grid-stride over float4s ----
        int stride = CAST_BLOCKS * 256;
        for (int i = (blockIdx.x - TP_BLOCKS) * 256 + t; i < ntot4; i += stride) {
            const float* src = (i < nk4) ? kin : win;
            _Float16* dst    = (i < nk4) ? Kh  : Wh;
            int j            = (i < nk4) ? i   : i - nk4;
            float4 v = reinterpret_cast<const float4*>(src)[j];
            half4v hh;
            hh[0] = (_Float16)v.x; hh[1] = (_Float16)v.y;
            hh[2] = (_Float16)v.z; hh[3] = (_Float16)v.w;
            reinterpret_cast<half4v*>(dst)[j] = hh;
        }
    }
}

// ---------------------------------------------------------------------------
// 64x64 f16 LDS tile staging (16B-chunk XOR swizzle, inverse-swizzled source)
// ---------------------------------------------------------------------------
__device__ __forceinline__ void stage_gl(const _Float16* __restrict__ g,
                                         size_t stride, _Float16* lds,
                                         int w, int lane) {
    int r0 = lane >> 3;
    int c  = (lane & 7) ^ r0;
#pragma unroll
    for (int j = 0; j < 2; ++j) {
        int r = (w + 4 * j) * 8 + r0;
        const _Float16* src = g + (size_t)r * stride + c * 8;
        _Float16* dst = lds + (w + 4 * j) * 512;   // wave-uniform base
        __builtin_amdgcn_global_load_lds((const AS1 void*)src, (AS3 void*)dst,
                                         16, 0, 0);
    }
}

__device__ __forceinline__ half8 read_frag64(const _Float16* lds, int row, int chunk) {
    int csw = chunk ^ (row & 7);
    return *reinterpret_cast<const half8*>(lds + row * 64 + csw * 8);
}

// Q B-fragment loader: B[k=(lg+4ks)*8+i][col=q=l15], pre-scaled by log2e/8
__device__ __forceinline__ void load_qfrag(const float* qsrc, int lg, half8* qf) {
#pragma unroll
    for (int ks = 0; ks < 2; ++ks) {
        float4 a0 = *reinterpret_cast<const float4*>(qsrc + (lg + 4 * ks) * 8);
        float4 a1 = *reinterpret_cast<const float4*>(qsrc + (lg + 4 * ks) * 8 + 4);
        qf[ks][0] = (_Float16)(a0.x * QSCALE); qf[ks][1] = (_Float16)(a0.y * QSCALE);
        qf[ks][2] = (_Float16)(a0.z * QSCALE); qf[ks][3] = (_Float16)(a0.w * QSCALE);
        qf[ks][4] = (_Float16)(a1.x * QSCALE); qf[ks][5] = (_Float16)(a1.y * QSCALE);
        qf[ks][6] = (_Float16)(a1.z * QSCALE); qf[ks][7] = (_Float16)(a1.w * QSCALE);
    }
}

// ---------------------------------------------------------------------------
// Fused attention (round-11 structure) + ROTATED s-tile order: block with
// q-tile index qt visits tile (t+qt)&31 at step t (pass 2) / pair-aligned
// rotation (pass 1). Stores and row-sums are order-independent, so this is
// semantically free; it de-phases the 4 resident blocks/CU so their
// BAR_VM store-drain / stage-wait points spread in time (anti-convoy).
// LDS-staged K/V, counted-vmcnt barriers, plain cacheable stores,
// XCD swizzle, setprio around MFMA clusters (both passes).
// Operand-swapped QK^T: lane (l15,lg) holds S[q=l15][s=ct*16+lg*4+r].
// ---------------------------------------------------------------------------
__global__ __launch_bounds__(256) void attn_kernel(
        const float* __restrict__ Q, const _Float16* __restrict__ Kh,
        const _Float16* __restrict__ Vt, float* __restrict__ attn_out,
        _Float16* __restrict__ head_h) {
    __shared__ __align__(16) _Float16 kbuf[2][64 * 64];
    __shared__ __align__(16) _Float16 vbuf[2][64 * 64];
    __shared__ __align__(16) _Float16 pbuf[4][16 * 64];

    int tid  = threadIdx.x;
    int wq   = tid >> 6;
    int lane = tid & 63;
    int l15  = lane & 15;
    int lg   = lane >> 4;

    // XCD swizzle: xcd = flat&7 hosts bh {4*xcd .. 4*xcd+3}; qt = (flat>>3)&31
    int flat = blockIdx.x;
    int bh   = (flat & 7) * 4 + (flat >> 8);
    int qt   = (flat >> 3) & 31;
    int q0   = qt * 64;
    int b = bh >> 4, h = bh & 15;

    const float* qsrc = Q + ((size_t)(b * T_DIM + q0 + wq * 16 + l15)) * E_DIM + h * D_HEAD;
    half8 qfrag[2];
    load_qfrag(qsrc, lg, qfrag);

    const _Float16* kg = Kh + ((size_t)b * T_DIM) * E_DIM + h * D_HEAD;
    const _Float16* vg = Vt + (size_t)bh * D_HEAD * T_DIM;

#define P1TILE(KB)                                                             \
    {                                                                          \
        f32x4 acc[4];                                                          \
        _Pragma("unroll")                                                      \
        for (int ct = 0; ct < 4; ++ct) acc[ct] = (f32x4){0.f, 0.f, 0.f, 0.f};  \
        __builtin_amdgcn_s_setprio(1);                                         \
        _Pragma("unroll")                                                      \
        for (int ks = 0; ks < 2; ++ks)                                         \
            _Pragma("unroll")                                                  \
            for (int ct = 0; ct < 4; ++ct) {                                   \
                half8 kf = read_frag64((KB), ct * 16 + l15, lg + 4 * ks);      \
                acc[ct] = __builtin_amdgcn_mfma_f32_16x16x32_f16(              \
                    kf, qfrag[ks], acc[ct], 0, 0, 0);                          \
            }                                                                  \
        __builtin_amdgcn_s_setprio(0);                                         \
        _Pragma("unroll")                                                      \
        for (int ct = 0; ct < 4; ++ct)                                         \
            _Pragma("unroll")                                                  \
            for (int r = 0; r < 4; ++r)                                        \
                lsum += __builtin_amdgcn_exp2f(acc[ct][r]);                    \
    }

    // ---------------- pass 1: row sums (double-tile phases, rotated) -------
    // rot2 even keeps pairs (even,odd)-aligned. idx(n) = (n + rot2) & 31.
    int rot2 = (qt << 1) & 31;          // 0,2,4,...,30 (even)
#define IDX1(n) (((n) + rot2) & 31)
    float lsum = 0.0f;
    stage_gl(kg + (size_t)IDX1(0) * 64 * E_DIM, E_DIM, kbuf[0], wq, lane);
    stage_gl(kg + (size_t)IDX1(1) * 64 * E_DIM, E_DIM, kbuf[1], wq, lane);
    for (int tt = 0; tt < NT / 2; tt += 2) {
        // phase A: compute pair in kbuf (tiles 2tt,2tt+1); stage pair B
        {
            stage_gl(kg + (size_t)IDX1(2 * tt + 2) * 64 * E_DIM, E_DIM, vbuf[0], wq, lane);
            stage_gl(kg + (size_t)IDX1(2 * tt + 3) * 64 * E_DIM, E_DIM, vbuf[1], wq, lane);
            BAR_VM(4);
            P1TILE(kbuf[0]);
            P1TILE(kbuf[1]);
            bar_plain();
        }
        // phase B: compute pair in vbuf (tiles 2tt+2,2tt+3); stage pair A
        {
            if (tt + 2 < NT / 2) {
                stage_gl(kg + (size_t)IDX1(2 * tt + 4) * 64 * E_DIM, E_DIM, kbuf[0], wq, lane);
                stage_gl(kg + (size_t)IDX1(2 * tt + 5) * 64 * E_DIM, E_DIM, kbuf[1], wq, lane);
                BAR_VM(4);
            } else {
                BAR_VM(0);
            }
            P1TILE(vbuf[0]);
            P1TILE(vbuf[1]);
            bar_plain();
        }
    }
#undef IDX1

    // reduce across the 4 lg replicas of each q row
    lsum += __shfl_xor(lsum, 16);
    lsum += __shfl_xor(lsum, 32);
    float rl = 1.0f / lsum;

    f32x4 oacc[4];
#pragma unroll
    for (int cd = 0; cd < 4; ++cd) oacc[cd] = (f32x4){0.f, 0.f, 0.f, 0.f};

    float* ab = attn_out + (size_t)bh * T_DIM * T_DIM;
    _Float16* pw = pbuf[wq];
    int myq = q0 + wq * 16 + l15;

    // ---------------- pass 2: P write + PV (rotated order) ----------------
    // phys = (t + qt) & 31. FIFO per tile: stage(t)=4 (K2+V2), stores(t)=4.
    // After stage(t): t==0 -> 4; steady -> stores(t-1)+stage(t+1)=8; last -> 4.
    int cur = 0;
    {
        int p0 = qt & 31;
        stage_gl(kg + (size_t)p0 * 64 * E_DIM, E_DIM, kbuf[0], wq, lane);
        stage_gl(vg + p0 * 64, T_DIM, vbuf[0], wq, lane);
    }
    for (int t = 0; t < NT; ++t) {
        int phys = (t + qt) & 31;
        if (t < NT - 1) {
            int pn = (t + 1 + qt) & 31;
            stage_gl(kg + (size_t)pn * 64 * E_DIM, E_DIM, kbuf[cur ^ 1], wq, lane);
            stage_gl(vg + pn * 64, T_DIM, vbuf[cur ^ 1], wq, lane);
        }
        if (t == 0)           BAR_VM(4);
        else if (t < NT - 1)  BAR_VM(8);   // P-stores ride 2 tiles in flight
        else                  BAR_VM(4);
        const _Float16* kb = kbuf[cur];
        const _Float16* vb = vbuf[cur];

        f32x4 acc[4];
#pragma unroll
        for (int ct = 0; ct < 4; ++ct) acc[ct] = (f32x4){0.f, 0.f, 0.f, 0.f};
        __builtin_amdgcn_s_setprio(1);
#pragma unroll
        for (int ks = 0; ks < 2; ++ks)
#pragma unroll
            for (int ct = 0; ct < 4; ++ct) {
                half8 kf = read_frag64(kb, ct * 16 + l15, lg + 4 * ks);
                acc[ct] = __builtin_amdgcn_mfma_f32_16x16x32_f16(kf, qfrag[ks], acc[ct], 0, 0, 0);
            }
        __builtin_amdgcn_s_setprio(0);

        // P: one plain dwordx4 global store (L2 write-combined) + b64 pbuf
        float* abrow = ab + (size_t)myq * T_DIM + phys * 64 + lg * 4;
#pragma unroll
        for (int ct = 0; ct < 4; ++ct) {
            f32x4 p;
            p[0] = __builtin_amdgcn_exp2f(acc[ct][0]) * rl;
            p[1] = __builtin_amdgcn_exp2f(acc[ct][1]) * rl;
            p[2] = __builtin_amdgcn_exp2f(acc[ct][2]) * rl;
            p[3] = __builtin_amdgcn_exp2f(acc[ct][3]) * rl;
            *reinterpret_cast<f32x4*>(abrow + ct * 16) = p;
            half4v ph;
            ph[0] = (_Float16)p[0]; ph[1] = (_Float16)p[1];
            ph[2] = (_Float16)p[2]; ph[3] = (_Float16)p[3];
            int cc = (ct * 4 + lg) ^ l15;          // 4-bit XOR: bank-balanced
            *reinterpret_cast<half4v*>(pw + l15 * 64 + cc * 4) = ph;
        }

        // PV: A = P[q=l15][s], B = V[s][d] (vbuf rows are d from Vt)
        __builtin_amdgcn_s_setprio(1);
#pragma unroll
        for (int ks = 0; ks < 2; ++ks) {
            int c0 = 2 * (lg + 4 * ks);
            half4v lo = *reinterpret_cast<const half4v*>(pw + l15 * 64 + ((c0)     ^ l15) * 4);
            half4v hi = *reinterpret_cast<const half4v*>(pw + l15 * 64 + ((c0 + 1) ^ l15) * 4);
            half8 pa;
            pa[0] = lo[0]; pa[1] = lo[1]; pa[2] = lo[2]; pa[3] = lo[3];
            pa[4] = hi[0]; pa[5] = hi[1]; pa[6] = hi[2]; pa[7] = hi[3];
#pragma unroll
            for (int cd = 0; cd < 4; ++cd) {
                half8 vf = read_frag64(vb, cd * 16 + l15, lg + 4 * ks);
                oacc[cd] = __builtin_amdgcn_mfma_f32_16x16x32_f16(pa, vf, oacc[cd], 0, 0, 0);
            }
        }
        __builtin_amdgcn_s_setprio(0);
        bar_plain();                   // buf[cur] reads done; next overwrite ok
        cur ^= 1;
    }

    // head (f16) -> workspace [B*T][E]; O[q=lg*4+r][d=cd*16+l15]
    _Float16* hw = head_h + ((size_t)(b * T_DIM + q0 + wq * 16)) * E_DIM + h * D_HEAD;
#pragma unroll
    for (int cd = 0; cd < 4; ++cd)
#pragma unroll
        for (int r = 0; r < 4; ++r) {
            int qm = lg * 4 + r;
            hw[(size_t)qm * E_DIM + cd * 16 + l15] = (_Float16)oacc[cd][r];
        }
#undef P1TILE
}

// ---------------------------------------------------------------------------
// outputs[m][n] = sum_k head[m][k]*W[n][k]  (M=4096,N=1024,K=1024)
// Operand-swapped: acc = mfma(A=W_frag, B=head_frag) -> dwordx4 C stores.
// ---------------------------------------------------------------------------
__global__ __launch_bounds__(256) void proj_kernel(
        const _Float16* __restrict__ A, const _Float16* __restrict__ Wh,
        float* __restrict__ out) {
    __shared__ __align__(16) _Float16 abuf[2][64 * 64];
    __shared__ __align__(16) _Float16 bbuf[2][64 * 64];

    int tid  = threadIdx.x;
    int wq   = tid >> 6;
    int lane = tid & 63;
    int l15  = lane & 15;
    int lg   = lane >> 4;

    int m0 = blockIdx.x * 64;
    int n0 = blockIdx.y * 64;

    f32x4 acc[4];
#pragma unroll
    for (int ct = 0; ct < 4; ++ct) acc[ct] = (f32x4){0.f, 0.f, 0.f, 0.f};

    int cur = 0;
    stage_gl(A  + (size_t)m0 * E_DIM, E_DIM, abuf[0], wq, lane);
    stage_gl(Wh + (size_t)n0 * E_DIM, E_DIM, bbuf[0], wq, lane);
    for (int t = 0; t < E_DIM / 64; ++t) {
        if (t + 1 < E_DIM / 64) {
            stage_gl(A  + (size_t)m0 * E_DIM + (t + 1) * 64, E_DIM, abuf[cur ^ 1], wq, lane);
            stage_gl(Wh + (size_t)n0 * E_DIM + (t + 1) * 64, E_DIM, bbuf[cur ^ 1], wq, lane);
            BAR_VM(4);                 // 4 ops issued after stage(t)
        } else {
            BAR_VM(0);
        }
#pragma unroll
        for (int ks = 0; ks < 2; ++ks) {
            half8 hf = read_frag64(abuf[cur], wq * 16 + l15, lg + 4 * ks);
#pragma unroll
            for (int ct = 0; ct < 4; ++ct) {
                half8 wf = read_frag64(bbuf[cur], ct * 16 + l15, lg + 4 * ks);
                acc[ct] = __builtin_amdgcn_mfma_f32_16x16x32_f16(wf, hf, acc[ct], 0, 0, 0);
            }
        }
        bar_plain();                   // buf[cur] reads done before overwrite
        cur ^= 1;
    }

    float* orow = out + (size_t)(m0 + wq * 16 + l15) * E_DIM + n0 + lg * 4;
#pragma unroll
    for (int ct = 0; ct < 4; ++ct) {
        f32x4 o;
        o[0] = acc[ct][0]; o[1] = acc[ct][1]; o[2] = acc[ct][2]; o[3] = acc[ct][3];
        *reinterpret_cast<f32x4*>(orow + ct * 16) = o;
    }
}

// ---------------------------------------------------------------------------
extern "C" void kernel_launch(void* const* d_in, const int* in_sizes, int n_in,
                              void* d_out, int out_size, void* d_ws, size_t ws_size,
                              hipStream_t stream) {
    const float* q = (const float*)d_in[0];
    const float* k = (const float*)d_in[1];
    const float* v = (const float*)d_in[2];
    const float* w = (const float*)d_in[3];

    float* outs = (float*)d_out;
    float* attn = outs + (size_t)B_NUM * T_DIM * E_DIM;   // [32,2048,2048]

    char* ws = (char*)d_ws;
    _Float16* Kh = (_Float16*)(ws);                       //  8 MiB @ 0
    _Float16* Vt = (_Float16*)(ws + (size_t)(8  << 20));  //  8 MiB
    _Float16* Wh = (_Float16*)(ws + (size_t)(16 << 20));  //  2 MiB
    _Float16* Hh = (_Float16*)(ws + (size_t)(18 << 20));  //  8 MiB

    int nk4 = B_NUM * T_DIM * E_DIM / 4;     // 1,048,576
    int nw4 = E_DIM * E_DIM / 4;             //   262,144

    prep_kernel<<<TP_BLOCKS + CAST_BLOCKS, 256, 0, stream>>>(
        k, w, v, Kh, Wh, Vt, nk4, nk4 + nw4);
    attn_kernel<<<NT * BH_NUM, 256, 0, stream>>>(q, Kh, Vt, attn, Hh);
    proj_kernel<<<dim3((B_NUM * T_DIM) / 64, E_DIM / 64), 256, 0, stream>>>(Hh, Wh, outs);
}